// Round 11
// baseline (100.184 us; speedup 1.0000x reference)
//
#include <hip/hip_runtime.h>
#include <hip/hip_bf16.h>
#include <math.h>
#include <stdint.h>

#define NT 256
constexpr int Hc = 1024, BOTc = 128, RDc = 48, Nc = 4096;
constexpr int ROWS = 8192;          // B*S
constexpr float INV_SQRT_RD = 0.14433756729740643f;  // 1/sqrt(48)

typedef short bf16x8 __attribute__((ext_vector_type(8)));
typedef float f32x4 __attribute__((ext_vector_type(4)));

// ---------- small helpers ----------
__device__ __forceinline__ uint32_t umin32(uint32_t a, uint32_t b) { return a < b ? a : b; }
__device__ __forceinline__ uint32_t umax32(uint32_t a, uint32_t b) { return a > b ? a : b; }
__device__ __forceinline__ void ce_asc(uint32_t& x, uint32_t& y) {
  uint32_t lo = umin32(x, y), hi = umax32(x, y); x = lo; y = hi;
}
__device__ __forceinline__ uint32_t pack_score(float s, int slot) {
  uint32_t u = __float_as_uint(s);
  u = (u & 0x80000000u) ? ~u : (u | 0x80000000u);
  return (u & 0xFFFFF000u) | (uint32_t)slot;
}
__device__ __forceinline__ float unpack_score(uint32_t p) {
  uint32_t m = p & 0xFFFFF000u;
  uint32_t f = (m & 0x80000000u) ? (m ^ 0x80000000u) : ~m;
  return __uint_as_float(f);
}
__device__ __forceinline__ void merge_top8(uint32_t a[8], const uint32_t b[8]) {
  uint32_t m[8];
#pragma unroll
  for (int i = 0; i < 8; ++i) m[i] = umax32(a[i], b[7 - i]);
  ce_asc(m[0], m[4]); ce_asc(m[1], m[5]); ce_asc(m[2], m[6]); ce_asc(m[3], m[7]);
  ce_asc(m[0], m[2]); ce_asc(m[1], m[3]); ce_asc(m[4], m[6]); ce_asc(m[5], m[7]);
  ce_asc(m[0], m[1]); ce_asc(m[2], m[3]); ce_asc(m[4], m[5]); ce_asc(m[6], m[7]);
#pragma unroll
  for (int i = 0; i < 8; ++i) a[i] = m[i];
}
__device__ __forceinline__ void top8_insert(uint32_t top[8], uint32_t p) {
  if (p > top[0]) {
    top[0] = p;
    ce_asc(top[0], top[1]); ce_asc(top[1], top[2]); ce_asc(top[2], top[3]);
    ce_asc(top[3], top[4]); ce_asc(top[4], top[5]); ce_asc(top[5], top[6]);
    ce_asc(top[6], top[7]);
  }
}
__device__ __forceinline__ uint16_t bf16bits(float x) {      // RNE
  uint32_t u = __float_as_uint(x);
  return (uint16_t)(((u + 0x7FFFu + ((u >> 16) & 1u)) >> 16) & 0xFFFFu);
}
__device__ __forceinline__ float bf2f(uint16_t h) {
  return __uint_as_float((uint32_t)h << 16);
}
__device__ __forceinline__ bf16x8 cvt8(float4 a, float4 b) {
  bf16x8 r;
  r[0] = (short)bf16bits(a.x); r[1] = (short)bf16bits(a.y);
  r[2] = (short)bf16bits(a.z); r[3] = (short)bf16bits(a.w);
  r[4] = (short)bf16bits(b.x); r[5] = (short)bf16bits(b.y);
  r[6] = (short)bf16bits(b.z); r[7] = (short)bf16bits(b.w);
  return r;
}

// ---------- prep: w48 + rk + cvt(w1) + cvt(aux_values) ----------
constexpr int GP_W48 = 64, GP_RK = 768, GP_CVW = 32, GP_CVA = 512;
__global__ __launch_bounds__(256) void k_prep_all(
    const float* __restrict__ q_proj_w, const float* __restrict__ router_w,
    const float* __restrict__ aux_keys, const float* __restrict__ aux_values,
    const float* __restrict__ rel, const float* __restrict__ unc_w1,
    uint16_t* __restrict__ wcat, uint16_t* __restrict__ avb,
    uint16_t* __restrict__ rk_b) {
  int bid = blockIdx.x;
  int tid = threadIdx.x;
  if (bid < GP_W48) {
    __shared__ float rw[BOTc];
    int j = bid;
    if (j >= RDc) {
      for (int hh = tid; hh < Hc; hh += NT) wcat[(size_t)(256 + j) * Hc + hh] = 0;
      return;
    }
    for (int d = tid; d < BOTc; d += NT) rw[d] = router_w[j * BOTc + d];
    __syncthreads();
    float acc[4] = {0.f, 0.f, 0.f, 0.f};
#pragma unroll 4
    for (int d = 0; d < BOTc; ++d) {
      float r = rw[d];
#pragma unroll
      for (int jj = 0; jj < 4; ++jj)
        acc[jj] = fmaf(r, q_proj_w[d * Hc + tid + 256 * jj], acc[jj]);
    }
#pragma unroll
    for (int jj = 0; jj < 4; ++jj)
      wcat[(size_t)(256 + j) * Hc + tid + 256 * jj] = bf16bits(acc[jj]);
    return;
  }
  bid -= GP_W48;
  if (bid < GP_RK) {
    int gid = bid * NT + tid;
    int n = gid / RDc, r = gid - n * RDc;
    float acc = 0.f;
#pragma unroll 8
    for (int d = 0; d < BOTc; ++d)
      acc = fmaf(aux_keys[n * BOTc + d], router_w[r * BOTc + d], acc);
    rk_b[(size_t)n * 64 + r] = bf16bits(acc * INV_SQRT_RD);
    if (r < 16) rk_b[(size_t)n * 64 + 48 + r] = (r == 0) ? bf16bits(rel[n]) : (uint16_t)0;
    return;
  }
  bid -= GP_RK;
  if (bid < GP_CVW) {
    float4 v[8];
    int base = bid * 2048 + tid;
#pragma unroll
    for (int i = 0; i < 8; ++i) v[i] = reinterpret_cast<const float4*>(unc_w1)[base + i * 256];
#pragma unroll
    for (int i = 0; i < 8; ++i) {
      ushort4 h;
      h.x = bf16bits(v[i].x); h.y = bf16bits(v[i].y);
      h.z = bf16bits(v[i].z); h.w = bf16bits(v[i].w);
      reinterpret_cast<ushort4*>(wcat)[base + i * 256] = h;
    }
    return;
  }
  bid -= GP_CVW;
  {
    float4 v[8];
    int base = bid * 2048 + tid;
#pragma unroll
    for (int i = 0; i < 8; ++i) v[i] = reinterpret_cast<const float4*>(aux_values)[base + i * 256];
#pragma unroll
    for (int i = 0; i < 8; ++i) {
      ushort4 h;
      h.x = bf16bits(v[i].x); h.y = bf16bits(v[i].y);
      h.z = bf16bits(v[i].z); h.w = bf16bits(v[i].w);
      reinterpret_cast<ushort4*>(avb)[base + i * 256] = h;
    }
  }
}

// ---------- fused rq + uncertainty GEMM, reading hidden fp32 directly ----------
// 640 blocks (8x80 XCD-bijective) = rowg(128 x 64rows) x colg(5 x 64cols of wcat).
// colg 0-3: unc cols; colg 4: rq (wcat rows 256-319, col48 -> 1.0).
// colg==0 additionally computes per-row variance -> log_var (sees full K during staging).
__global__ __launch_bounds__(256) void k_xw(const float* __restrict__ hidden,
                                            const uint16_t* __restrict__ wcat,
                                            const float* __restrict__ b1,
                                            const float* __restrict__ w2,
                                            float* __restrict__ log_var,
                                            float* __restrict__ uncp,
                                            uint16_t* __restrict__ rq_b) {
  __shared__ uint16_t As[2][64 * 72];
  __shared__ uint16_t Bs[2][64 * 72];
  int bid = blockIdx.x;
  int tid = threadIdx.x;
  int wid = (bid & 7) * 80 + (bid >> 3);             // XCD-contiguous (640 = 8*80)
  int rowg = wid / 5, colg = wid - rowg * 5;
  int wave = tid >> 6, lane = tid & 63;
  int l15 = lane & 15, lg = lane >> 4;
  int wr = wave >> 1, wc = wave & 1;
  int row0 = rowg * 64, n0 = colg * 64;
  int srow = tid >> 3, sseg = tid & 7;
  const float* agp0 = hidden + (size_t)(row0 + srow) * Hc + sseg * 8;
  const float* agp1 = agp0 + (size_t)32 * Hc;
  const uint16_t* bgp = wcat + (size_t)(n0 + srow) * Hc + sseg * 8;
  int sboff = srow * 72 + sseg * 8;
  int arow = wr * 32 + l15, brow = wc * 32 + l15;
  bool dovar = (colg == 0);
  float vs0 = 0.f, vq0 = 0.f, vs1 = 0.f, vq1 = 0.f;

  // stage A = even tiles, stage B = odd tiles (prefetch distance 2)
  float4 xA0a = *reinterpret_cast<const float4*>(agp0);
  float4 xA0b = *reinterpret_cast<const float4*>(agp0 + 4);
  float4 xA1a = *reinterpret_cast<const float4*>(agp1);
  float4 xA1b = *reinterpret_cast<const float4*>(agp1 + 4);
  bf16x8 wA0 = *reinterpret_cast<const bf16x8*>(bgp);
  bf16x8 wA1 = *reinterpret_cast<const bf16x8*>(bgp + (size_t)32 * Hc);
  float4 xB0a = *reinterpret_cast<const float4*>(agp0 + 64);
  float4 xB0b = *reinterpret_cast<const float4*>(agp0 + 68);
  float4 xB1a = *reinterpret_cast<const float4*>(agp1 + 64);
  float4 xB1b = *reinterpret_cast<const float4*>(agp1 + 68);
  bf16x8 wB0 = *reinterpret_cast<const bf16x8*>(bgp + 64);
  bf16x8 wB1 = *reinterpret_cast<const bf16x8*>(bgp + (size_t)32 * Hc + 64);
  f32x4 acc00 = {0.f,0.f,0.f,0.f}, acc01 = {0.f,0.f,0.f,0.f};
  f32x4 acc10 = {0.f,0.f,0.f,0.f}, acc11 = {0.f,0.f,0.f,0.f};

  for (int tt = 0; tt < 16; tt += 2) {
    // even step: buf 0, stage A
    *reinterpret_cast<bf16x8*>(&As[0][sboff]) = cvt8(xA0a, xA0b);
    *reinterpret_cast<bf16x8*>(&As[0][sboff + 32 * 72]) = cvt8(xA1a, xA1b);
    *reinterpret_cast<bf16x8*>(&Bs[0][sboff]) = wA0;
    *reinterpret_cast<bf16x8*>(&Bs[0][sboff + 32 * 72]) = wA1;
    if (dovar) {
      vs0 += xA0a.x + xA0a.y + xA0a.z + xA0a.w + xA0b.x + xA0b.y + xA0b.z + xA0b.w;
      vq0 += xA0a.x*xA0a.x + xA0a.y*xA0a.y + xA0a.z*xA0a.z + xA0a.w*xA0a.w
           + xA0b.x*xA0b.x + xA0b.y*xA0b.y + xA0b.z*xA0b.z + xA0b.w*xA0b.w;
      vs1 += xA1a.x + xA1a.y + xA1a.z + xA1a.w + xA1b.x + xA1b.y + xA1b.z + xA1b.w;
      vq1 += xA1a.x*xA1a.x + xA1a.y*xA1a.y + xA1a.z*xA1a.z + xA1a.w*xA1a.w
           + xA1b.x*xA1b.x + xA1b.y*xA1b.y + xA1b.z*xA1b.z + xA1b.w*xA1b.w;
    }
    if (tt + 2 < 16) {
      int k0 = (tt + 2) * 64;
      xA0a = *reinterpret_cast<const float4*>(agp0 + k0);
      xA0b = *reinterpret_cast<const float4*>(agp0 + k0 + 4);
      xA1a = *reinterpret_cast<const float4*>(agp1 + k0);
      xA1b = *reinterpret_cast<const float4*>(agp1 + k0 + 4);
      wA0 = *reinterpret_cast<const bf16x8*>(bgp + k0);
      wA1 = *reinterpret_cast<const bf16x8*>(bgp + (size_t)32 * Hc + k0);
    }
    __syncthreads();
#pragma unroll
    for (int ks = 0; ks < 2; ++ks) {
      bf16x8 a0 = *reinterpret_cast<const bf16x8*>(&As[0][arow * 72 + ks * 32 + lg * 8]);
      bf16x8 a1 = *reinterpret_cast<const bf16x8*>(&As[0][(arow + 16) * 72 + ks * 32 + lg * 8]);
      bf16x8 b0 = *reinterpret_cast<const bf16x8*>(&Bs[0][brow * 72 + ks * 32 + lg * 8]);
      bf16x8 b1f = *reinterpret_cast<const bf16x8*>(&Bs[0][(brow + 16) * 72 + ks * 32 + lg * 8]);
      acc00 = __builtin_amdgcn_mfma_f32_16x16x32_bf16(a0, b0, acc00, 0, 0, 0);
      acc01 = __builtin_amdgcn_mfma_f32_16x16x32_bf16(a0, b1f, acc01, 0, 0, 0);
      acc10 = __builtin_amdgcn_mfma_f32_16x16x32_bf16(a1, b0, acc10, 0, 0, 0);
      acc11 = __builtin_amdgcn_mfma_f32_16x16x32_bf16(a1, b1f, acc11, 0, 0, 0);
    }
    // odd step: buf 1, stage B
    *reinterpret_cast<bf16x8*>(&As[1][sboff]) = cvt8(xB0a, xB0b);
    *reinterpret_cast<bf16x8*>(&As[1][sboff + 32 * 72]) = cvt8(xB1a, xB1b);
    *reinterpret_cast<bf16x8*>(&Bs[1][sboff]) = wB0;
    *reinterpret_cast<bf16x8*>(&Bs[1][sboff + 32 * 72]) = wB1;
    if (dovar) {
      vs0 += xB0a.x + xB0a.y + xB0a.z + xB0a.w + xB0b.x + xB0b.y + xB0b.z + xB0b.w;
      vq0 += xB0a.x*xB0a.x + xB0a.y*xB0a.y + xB0a.z*xB0a.z + xB0a.w*xB0a.w
           + xB0b.x*xB0b.x + xB0b.y*xB0b.y + xB0b.z*xB0b.z + xB0b.w*xB0b.w;
      vs1 += xB1a.x + xB1a.y + xB1a.z + xB1a.w + xB1b.x + xB1b.y + xB1b.z + xB1b.w;
      vq1 += xB1a.x*xB1a.x + xB1a.y*xB1a.y + xB1a.z*xB1a.z + xB1a.w*xB1a.w
           + xB1b.x*xB1b.x + xB1b.y*xB1b.y + xB1b.z*xB1b.z + xB1b.w*xB1b.w;
    }
    if (tt + 3 < 16) {
      int k0 = (tt + 3) * 64;
      xB0a = *reinterpret_cast<const float4*>(agp0 + k0);
      xB0b = *reinterpret_cast<const float4*>(agp0 + k0 + 4);
      xB1a = *reinterpret_cast<const float4*>(agp1 + k0);
      xB1b = *reinterpret_cast<const float4*>(agp1 + k0 + 4);
      wB0 = *reinterpret_cast<const bf16x8*>(bgp + k0);
      wB1 = *reinterpret_cast<const bf16x8*>(bgp + (size_t)32 * Hc + k0);
    }
    __syncthreads();
#pragma unroll
    for (int ks = 0; ks < 2; ++ks) {
      bf16x8 a0 = *reinterpret_cast<const bf16x8*>(&As[1][arow * 72 + ks * 32 + lg * 8]);
      bf16x8 a1 = *reinterpret_cast<const bf16x8*>(&As[1][(arow + 16) * 72 + ks * 32 + lg * 8]);
      bf16x8 b0 = *reinterpret_cast<const bf16x8*>(&Bs[1][brow * 72 + ks * 32 + lg * 8]);
      bf16x8 b1f = *reinterpret_cast<const bf16x8*>(&Bs[1][(brow + 16) * 72 + ks * 32 + lg * 8]);
      acc00 = __builtin_amdgcn_mfma_f32_16x16x32_bf16(a0, b0, acc00, 0, 0, 0);
      acc01 = __builtin_amdgcn_mfma_f32_16x16x32_bf16(a0, b1f, acc01, 0, 0, 0);
      acc10 = __builtin_amdgcn_mfma_f32_16x16x32_bf16(a1, b0, acc10, 0, 0, 0);
      acc11 = __builtin_amdgcn_mfma_f32_16x16x32_bf16(a1, b1f, acc11, 0, 0, 0);
    }
  }
  // per-row variance (colg==0): reduce across the 8 staging lanes of each row
  if (dovar) {
#pragma unroll
    for (int d = 4; d >= 1; d >>= 1) {
      vs0 += __shfl_down(vs0, d); vq0 += __shfl_down(vq0, d);
      vs1 += __shfl_down(vs1, d); vq1 += __shfl_down(vq1, d);
    }
    if ((lane & 7) == 0) {
      float m0 = vs0 * (1.f / Hc), m1 = vs1 * (1.f / Hc);
      log_var[row0 + srow]      = log1pf(vq0 * (1.f / Hc) - m0 * m0);
      log_var[row0 + srow + 32] = log1pf(vq1 * (1.f / Hc) - m1 * m1);
    }
  }
  if (colg < 4) {
    int gc0 = n0 + wc * 32 + l15;
    float b1v0 = b1[gc0],      w2v0 = w2[gc0];
    float b1v1 = b1[gc0 + 16], w2v1 = w2[gc0 + 16];
    int strip = colg * 2 + wc;
    float part0[4], part1[4];
#pragma unroll
    for (int r = 0; r < 4; ++r) {
      float x00 = acc00[r] + b1v0, x01 = acc01[r] + b1v1;
      float x10 = acc10[r] + b1v0, x11 = acc11[r] + b1v1;
      float g00 = 0.5f * x00 * (1.f + erff(x00 * 0.70710678118654752f));
      float g01 = 0.5f * x01 * (1.f + erff(x01 * 0.70710678118654752f));
      float g10 = 0.5f * x10 * (1.f + erff(x10 * 0.70710678118654752f));
      float g11 = 0.5f * x11 * (1.f + erff(x11 * 0.70710678118654752f));
      part0[r] = fmaf(g00, w2v0, g01 * w2v1);
      part1[r] = fmaf(g10, w2v0, g11 * w2v1);
    }
#pragma unroll
    for (int d = 1; d < 16; d <<= 1)
#pragma unroll
      for (int r = 0; r < 4; ++r) {
        part0[r] += __shfl_xor(part0[r], d);
        part1[r] += __shfl_xor(part1[r], d);
      }
    if (l15 == 0) {
#pragma unroll
      for (int r = 0; r < 4; ++r) {
        uncp[(size_t)(row0 + wr * 32 + lg * 4 + r) * 8 + strip] = part0[r];
        uncp[(size_t)(row0 + wr * 32 + 16 + lg * 4 + r) * 8 + strip] = part1[r];
      }
    }
  } else {
    int colA = wc * 32 + l15, colB = colA + 16;
#pragma unroll
    for (int r = 0; r < 4; ++r) {
      int rA = row0 + wr * 32 + lg * 4 + r, rB = rA + 16;
      uint16_t vA = bf16bits(acc00[r]);
      uint16_t vB = (colB == 48) ? (uint16_t)0x3F80u : bf16bits(acc01[r]);
      uint16_t uA = bf16bits(acc10[r]);
      uint16_t uB = (colB == 48) ? (uint16_t)0x3F80u : bf16bits(acc11[r]);
      rq_b[(size_t)rA * 64 + colA] = vA;
      rq_b[(size_t)rA * 64 + colB] = vB;
      rq_b[(size_t)rB * 64 + colA] = uA;
      rq_b[(size_t)rB * 64 + colB] = uB;
    }
  }
}

// ---------- scores via MFMA + in-register top-8; block 1024 = redsum ----------
__global__ __launch_bounds__(256) void k_scores_mfma(const uint16_t* __restrict__ rq_b,
                                                     const uint16_t* __restrict__ rk_b,
                                                     uint32_t* __restrict__ cand,
                                                     const float* __restrict__ log_var,
                                                     float* __restrict__ stats) {
  int tid = threadIdx.x;
  if (blockIdx.x == 1024) {                          // folded redsum (log_var from k_xw)
    float s = 0.f;
    for (int i = tid; i < ROWS; i += NT) s += log_var[i];
#pragma unroll
    for (int d = 32; d >= 1; d >>= 1) s += __shfl_down(s, d);
    __shared__ float ls[4];
    int lane = tid & 63, wv = tid >> 6;
    if (lane == 0) ls[wv] = s;
    __syncthreads();
    if (tid == 0) {
      s = ls[0] + ls[1] + ls[2] + ls[3];
      stats[0] = 1.f / (s * (1.f / ROWS) + 1e-6f);
    }
    return;
  }
  int wave = tid >> 6, lane = tid & 63;
  int l15 = lane & 15, lg = lane >> 4;
  int rowg = blockIdx.x >> 3, range = blockIdx.x & 7;
  int q0 = rowg * 64 + wave * 16;
  const uint16_t* qp = rq_b + (size_t)(q0 + l15) * 64 + lg * 8;
  bf16x8 qf1 = *reinterpret_cast<const bf16x8*>(qp);
  bf16x8 qf2 = *reinterpret_cast<const bf16x8*>(qp + 32);
  uint32_t top[8];
#pragma unroll
  for (int q = 0; q < 8; ++q) top[q] = 0u;
  int sbase = range * 512;
  const uint16_t* kp = rk_b + (size_t)(sbase + l15) * 64 + lg * 8;
  bf16x8 a1c = *reinterpret_cast<const bf16x8*>(kp);
  bf16x8 a2c = *reinterpret_cast<const bf16x8*>(kp + 32);
  bf16x8 a3c = *reinterpret_cast<const bf16x8*>(kp + 1024);
  bf16x8 a4c = *reinterpret_cast<const bf16x8*>(kp + 1024 + 32);
#pragma unroll
  for (int t = 0; t < 32; t += 2) {
    bf16x8 a1n, a2n, a3n, a4n;
    if (t < 30) {
      const uint16_t* kpn = kp + (size_t)(t + 2) * 1024;
      a1n = *reinterpret_cast<const bf16x8*>(kpn);
      a2n = *reinterpret_cast<const bf16x8*>(kpn + 32);
      a3n = *reinterpret_cast<const bf16x8*>(kpn + 1024);
      a4n = *reinterpret_cast<const bf16x8*>(kpn + 1024 + 32);
    }
    int s0 = sbase + t * 16;
    f32x4 acc0 = {0.f,0.f,0.f,0.f}, acc1 = {0.f,0.f,0.f,0.f};
    acc0 = __builtin_amdgcn_mfma_f32_16x16x32_bf16(a1c, qf1, acc0, 0, 0, 0);
    acc1 = __builtin_amdgcn_mfma_f32_16x16x32_bf16(a3c, qf1, acc1, 0, 0, 0);
    acc0 = __builtin_amdgcn_mfma_f32_16x16x32_bf16(a2c, qf2, acc0, 0, 0, 0);
    acc1 = __builtin_amdgcn_mfma_f32_16x16x32_bf16(a4c, qf2, acc1, 0, 0, 0);
#pragma unroll
    for (int r = 0; r < 4; ++r) top8_insert(top, pack_score(acc0[r], s0 + lg * 4 + r));
#pragma unroll
    for (int r = 0; r < 4; ++r) top8_insert(top, pack_score(acc1[r], s0 + 16 + lg * 4 + r));
    if (t < 30) { a1c = a1n; a2c = a2n; a3c = a3n; a4c = a4n; }
  }
#pragma unroll
  for (int dd = 16; dd <= 32; dd <<= 1) {
    uint32_t o[8];
#pragma unroll
    for (int q = 0; q < 8; ++q) o[q] = __shfl_xor(top[q], dd);
    merge_top8(top, o);
  }
  if (lg == 0) {
    int row = q0 + l15;
#pragma unroll
    for (int q = 0; q < 8; ++q) cand[((size_t)row * 8 + range) * 8 + q] = top[q];
  }
}

// ---------- merge + softmax + gate + gather + output: 4 rows per block ----------
__global__ __launch_bounds__(256) void k_final(const float* __restrict__ hidden,
                                               const uint16_t* __restrict__ avb,
                                               const uint32_t* __restrict__ cand,
                                               const float* __restrict__ log_var,
                                               const float* __restrict__ uncp,
                                               const float* __restrict__ stats,
                                               const float* __restrict__ b2,
                                               const float* __restrict__ gw,
                                               const float* __restrict__ gb,
                                               float* __restrict__ out) {
  int tid = threadIdx.x;
  int wave = tid >> 6, lane = tid & 63;
  int row0 = blockIdx.x * 4;
  __shared__ float ws_[4][8]; __shared__ int wi_[4][8]; __shared__ float sg[4];
  {
    int row = row0 + wave;
    uint32_t l[8];
    float up = 0.f;
    if (lane < 8) {
      const uint32_t* c = cand + (size_t)row * 64 + lane * 8;
#pragma unroll
      for (int q = 0; q < 8; ++q) l[q] = c[q];
      up = uncp[(size_t)row * 8 + lane];
    } else {
#pragma unroll
      for (int q = 0; q < 8; ++q) l[q] = 0u;
    }
#pragma unroll
    for (int d = 1; d < 8; d <<= 1) {
      uint32_t o[8];
#pragma unroll
      for (int q = 0; q < 8; ++q) o[q] = __shfl_xor(l[q], d);
      merge_top8(l, o);
      up += __shfl_xor(up, d);
    }
    if (lane == 0) {
      float sc[8];
#pragma unroll
      for (int q = 0; q < 8; ++q) sc[q] = unpack_score(l[q]);
      float mx = sc[7];
      float e[8]; float sum = 0.f;
#pragma unroll
      for (int q = 0; q < 8; ++q) { e[q] = expf(sc[q] - mx); sum += e[q]; }
      float inv = 1.f / sum;
#pragma unroll
      for (int q = 0; q < 8; ++q) { ws_[wave][q] = e[q] * inv; wi_[wave][q] = (int)(l[q] & 0xFFFu); }
      float learned = up + b2[0];
      float nv = log_var[row] * stats[0];
      float sig = 1.f / (1.f + expf(-learned));
      float u = nv * 0.5f + sig * 2.5f;
      u = fminf(fmaxf(u, 0.f), 5.f);
      sg[wave] = 1.f / (1.f + expf(-(gw[0] * u + gb[0])));
    }
  }
  __syncthreads();
  int h0 = tid * 4;
#pragma unroll
  for (int rr = 0; rr < 4; ++rr) {
    int row = row0 + rr;
    float4 hv = *reinterpret_cast<const float4*>(hidden + (size_t)row * Hc + h0);
    float ax = 0.f, ay = 0.f, az = 0.f, aw = 0.f;
#pragma unroll
    for (int k = 0; k < 8; ++k) {
      float w = ws_[rr][k];
      ushort4 v = *reinterpret_cast<const ushort4*>(avb + (size_t)wi_[rr][k] * Hc + h0);
      ax = fmaf(w, bf2f(v.x), ax); ay = fmaf(w, bf2f(v.y), ay);
      az = fmaf(w, bf2f(v.z), az); aw = fmaf(w, bf2f(v.w), aw);
    }
    float g = sg[rr];
    float4 o;
    o.x = hv.x + g * ax; o.y = hv.y + g * ay;
    o.z = hv.z + g * az; o.w = hv.w + g * aw;
    *reinterpret_cast<float4*>(out + (size_t)row * Hc + h0) = o;
  }
}

extern "C" void kernel_launch(void* const* d_in, const int* in_sizes, int n_in,
                              void* d_out, int out_size, void* d_ws, size_t ws_size,
                              hipStream_t stream) {
  const float* hidden     = (const float*)d_in[0];
  const float* q_proj_w   = (const float*)d_in[1];
  const float* router_w   = (const float*)d_in[2];
  const float* aux_keys   = (const float*)d_in[3];
  const float* aux_values = (const float*)d_in[4];
  const float* rel        = (const float*)d_in[5];
  const float* unc_w1     = (const float*)d_in[6];
  const float* unc_b1     = (const float*)d_in[7];
  const float* unc_w2     = (const float*)d_in[8];
  const float* unc_b2     = (const float*)d_in[9];
  const float* gate_w1    = (const float*)d_in[10];
  const float* gate_bias  = (const float*)d_in[11];
  float* out = (float*)d_out;

  uint8_t* w = (uint8_t*)d_ws;              // ~12.5 MB used
  uint16_t* wcat  = (uint16_t*)w;                 w += (size_t)320 * Hc * 2;      // 640 KB
  uint16_t* avb   = (uint16_t*)w;                 w += (size_t)Nc * Hc * 2;       // 8 MB
  uint16_t* rq_b  = (uint16_t*)w;                 w += (size_t)ROWS * 64 * 2;     // 1 MB
  uint16_t* rk_b  = (uint16_t*)w;                 w += (size_t)Nc * 64 * 2;       // 512 KB
  float* log_var  = (float*)w;                    w += (size_t)ROWS * 4;
  float* uncp     = (float*)w;                    w += (size_t)ROWS * 8 * 4;      // 256 KB
  float* stats    = (float*)w;                    w += 256;
  uint32_t* cand  = (uint32_t*)w;                 w += (size_t)ROWS * 64 * 4;     // 2 MB

  k_prep_all<<<GP_W48 + GP_RK + GP_CVW + GP_CVA, NT, 0, stream>>>(
      q_proj_w, router_w, aux_keys, aux_values, rel, unc_w1, wcat, avb, rk_b);
  k_xw<<<640, NT, 0, stream>>>(hidden, wcat, unc_b1, unc_w2, log_var, uncp, rq_b);
  k_scores_mfma<<<1025, NT, 0, stream>>>(rq_b, rk_b, cand, log_var, stats);
  k_final<<<ROWS / 4, NT, 0, stream>>>(hidden, avb, cand, log_var, uncp,
                                       stats, unc_b2, gate_w1, gate_bias, out);
}

// Round 12
// 92.153 us; speedup vs baseline: 1.0871x; 1.0871x over previous
//
#include <hip/hip_runtime.h>
#include <hip/hip_bf16.h>
#include <math.h>
#include <stdint.h>

#define NT 256
constexpr int Hc = 1024, BOTc = 128, RDc = 48, Nc = 4096;
constexpr int ROWS = 8192;          // B*S
constexpr float INV_SQRT_RD = 0.14433756729740643f;  // 1/sqrt(48)

typedef short bf16x8 __attribute__((ext_vector_type(8)));
typedef float f32x4 __attribute__((ext_vector_type(4)));

// ---------- small helpers ----------
__device__ __forceinline__ uint32_t umin32(uint32_t a, uint32_t b) { return a < b ? a : b; }
__device__ __forceinline__ uint32_t umax32(uint32_t a, uint32_t b) { return a > b ? a : b; }
__device__ __forceinline__ void ce_asc(uint32_t& x, uint32_t& y) {
  uint32_t lo = umin32(x, y), hi = umax32(x, y); x = lo; y = hi;
}
__device__ __forceinline__ uint32_t pack_score(float s, int slot) {
  uint32_t u = __float_as_uint(s);
  u = (u & 0x80000000u) ? ~u : (u | 0x80000000u);
  return (u & 0xFFFFF000u) | (uint32_t)slot;
}
__device__ __forceinline__ float unpack_score(uint32_t p) {
  uint32_t m = p & 0xFFFFF000u;
  uint32_t f = (m & 0x80000000u) ? (m ^ 0x80000000u) : ~m;
  return __uint_as_float(f);
}
__device__ __forceinline__ void merge_top8(uint32_t a[8], const uint32_t b[8]) {
  uint32_t m[8];
#pragma unroll
  for (int i = 0; i < 8; ++i) m[i] = umax32(a[i], b[7 - i]);
  ce_asc(m[0], m[4]); ce_asc(m[1], m[5]); ce_asc(m[2], m[6]); ce_asc(m[3], m[7]);
  ce_asc(m[0], m[2]); ce_asc(m[1], m[3]); ce_asc(m[4], m[6]); ce_asc(m[5], m[7]);
  ce_asc(m[0], m[1]); ce_asc(m[2], m[3]); ce_asc(m[4], m[5]); ce_asc(m[6], m[7]);
#pragma unroll
  for (int i = 0; i < 8; ++i) a[i] = m[i];
}
__device__ __forceinline__ void top8_insert(uint32_t top[8], uint32_t p) {
  if (p > top[0]) {
    top[0] = p;
    ce_asc(top[0], top[1]); ce_asc(top[1], top[2]); ce_asc(top[2], top[3]);
    ce_asc(top[3], top[4]); ce_asc(top[4], top[5]); ce_asc(top[5], top[6]);
    ce_asc(top[6], top[7]);
  }
}
__device__ __forceinline__ uint16_t bf16bits(float x) {      // RNE
  uint32_t u = __float_as_uint(x);
  return (uint16_t)(((u + 0x7FFFu + ((u >> 16) & 1u)) >> 16) & 0xFFFFu);
}
__device__ __forceinline__ float bf2f(uint16_t h) {
  return __uint_as_float((uint32_t)h << 16);
}

// ---------- fused prep; latency-bound sections FIRST, then BW flood ----------
constexpr int GP_W48 = 64, GP_RK = 768, GP_HB = 1024, GP_CVW = 32, GP_CVA = 512;
__global__ __launch_bounds__(256) void k_prep_all(
    const float* __restrict__ hidden, const float* __restrict__ q_proj_w,
    const float* __restrict__ router_w, const float* __restrict__ aux_keys,
    const float* __restrict__ aux_values, const float* __restrict__ rel,
    const float* __restrict__ unc_w1,
    uint16_t* __restrict__ xb, float* __restrict__ log_var,
    uint16_t* __restrict__ wcat, uint16_t* __restrict__ avb,
    uint16_t* __restrict__ rk_b) {
  int bid = blockIdx.x;
  int tid = threadIdx.x;
  if (bid < GP_W48) {
    __shared__ float rw[BOTc];
    int j = bid;
    if (j >= RDc) {
      for (int hh = tid; hh < Hc; hh += NT) wcat[(size_t)(256 + j) * Hc + hh] = 0;
      return;
    }
    for (int d = tid; d < BOTc; d += NT) rw[d] = router_w[j * BOTc + d];
    __syncthreads();
    float acc[4] = {0.f, 0.f, 0.f, 0.f};
#pragma unroll 4
    for (int d = 0; d < BOTc; ++d) {
      float r = rw[d];
#pragma unroll
      for (int jj = 0; jj < 4; ++jj)
        acc[jj] = fmaf(r, q_proj_w[d * Hc + tid + 256 * jj], acc[jj]);
    }
#pragma unroll
    for (int jj = 0; jj < 4; ++jj)
      wcat[(size_t)(256 + j) * Hc + tid + 256 * jj] = bf16bits(acc[jj]);
    return;
  }
  bid -= GP_W48;
  if (bid < GP_RK) {
    int gid = bid * NT + tid;
    int n = gid / RDc, r = gid - n * RDc;
    float acc = 0.f;
#pragma unroll 8
    for (int d = 0; d < BOTc; ++d)
      acc = fmaf(aux_keys[n * BOTc + d], router_w[r * BOTc + d], acc);
    rk_b[(size_t)n * 64 + r] = bf16bits(acc * INV_SQRT_RD);
    if (r < 16) rk_b[(size_t)n * 64 + 48 + r] = (r == 0) ? bf16bits(rel[n]) : (uint16_t)0;
    return;
  }
  bid -= GP_RK;
  if (bid < GP_HB) {
    int wave = tid >> 6, lane = tid & 63;
    int row = bid * 8 + wave * 2;
    const float4* r0 = reinterpret_cast<const float4*>(hidden + (size_t)row * Hc);
    const float4* r1 = reinterpret_cast<const float4*>(hidden + (size_t)(row + 1) * Hc);
    float4 v0[4], v1[4];
#pragma unroll
    for (int i = 0; i < 4; ++i) v0[i] = r0[lane + 64 * i];
#pragma unroll
    for (int i = 0; i < 4; ++i) v1[i] = r1[lane + 64 * i];
    float s0 = 0.f, q0 = 0.f, s1 = 0.f, q1 = 0.f;
#pragma unroll
    for (int i = 0; i < 4; ++i) {
      ushort4 h;
      h.x = bf16bits(v0[i].x); h.y = bf16bits(v0[i].y);
      h.z = bf16bits(v0[i].z); h.w = bf16bits(v0[i].w);
      *reinterpret_cast<ushort4*>(xb + (size_t)row * Hc + (lane + 64 * i) * 4) = h;
      s0 += v0[i].x + v0[i].y + v0[i].z + v0[i].w;
      q0 += v0[i].x * v0[i].x + v0[i].y * v0[i].y + v0[i].z * v0[i].z + v0[i].w * v0[i].w;
    }
#pragma unroll
    for (int i = 0; i < 4; ++i) {
      ushort4 h;
      h.x = bf16bits(v1[i].x); h.y = bf16bits(v1[i].y);
      h.z = bf16bits(v1[i].z); h.w = bf16bits(v1[i].w);
      *reinterpret_cast<ushort4*>(xb + (size_t)(row + 1) * Hc + (lane + 64 * i) * 4) = h;
      s1 += v1[i].x + v1[i].y + v1[i].z + v1[i].w;
      q1 += v1[i].x * v1[i].x + v1[i].y * v1[i].y + v1[i].z * v1[i].z + v1[i].w * v1[i].w;
    }
#pragma unroll
    for (int d = 32; d >= 1; d >>= 1) {
      s0 += __shfl_down(s0, d); q0 += __shfl_down(q0, d);
      s1 += __shfl_down(s1, d); q1 += __shfl_down(q1, d);
    }
    if (lane == 0) {
      float m0 = s0 * (1.f / Hc), m1 = s1 * (1.f / Hc);
      log_var[row]     = log1pf(q0 * (1.f / Hc) - m0 * m0);
      log_var[row + 1] = log1pf(q1 * (1.f / Hc) - m1 * m1);
    }
    return;
  }
  bid -= GP_HB;
  if (bid < GP_CVW) {
    float4 v[8];
    int base = bid * 2048 + tid;
#pragma unroll
    for (int i = 0; i < 8; ++i) v[i] = reinterpret_cast<const float4*>(unc_w1)[base + i * 256];
#pragma unroll
    for (int i = 0; i < 8; ++i) {
      ushort4 h;
      h.x = bf16bits(v[i].x); h.y = bf16bits(v[i].y);
      h.z = bf16bits(v[i].z); h.w = bf16bits(v[i].w);
      reinterpret_cast<ushort4*>(wcat)[base + i * 256] = h;
    }
    return;
  }
  bid -= GP_CVW;
  {
    float4 v[8];
    int base = bid * 2048 + tid;
#pragma unroll
    for (int i = 0; i < 8; ++i) v[i] = reinterpret_cast<const float4*>(aux_values)[base + i * 256];
#pragma unroll
    for (int i = 0; i < 8; ++i) {
      ushort4 h;
      h.x = bf16bits(v[i].x); h.y = bf16bits(v[i].y);
      h.z = bf16bits(v[i].z); h.w = bf16bits(v[i].w);
      reinterpret_cast<ushort4*>(avb)[base + i * 256] = h;
    }
  }
}

// ---------- fused rq + uncertainty GEMM: LDS dbuf, prefetch-distance 2, 1 barrier/step ----------
// blocks 0-639 (8x80 XCD-bijective) = rowg(128 x 64rows) x colg(5 x 64cols of wcat).
// colg 0-3: unc cols; colg 4: rq (wcat rows 256-319, col48 -> 1.0). block 640: redsum.
__global__ __launch_bounds__(256) void k_xw(const uint16_t* __restrict__ xb,
                                            const uint16_t* __restrict__ wcat,
                                            const float* __restrict__ b1,
                                            const float* __restrict__ w2,
                                            const float* __restrict__ log_var,
                                            float* __restrict__ stats,
                                            float* __restrict__ uncp,
                                            uint16_t* __restrict__ rq_b) {
  int bid = blockIdx.x;
  int tid = threadIdx.x;
  if (bid == 640) {                                  // folded redsum (log_var from prep)
    float s = 0.f;
    for (int i = tid; i < ROWS; i += NT) s += log_var[i];
#pragma unroll
    for (int d = 32; d >= 1; d >>= 1) s += __shfl_down(s, d);
    __shared__ float ls[4];
    int lane = tid & 63, wv = tid >> 6;
    if (lane == 0) ls[wv] = s;
    __syncthreads();
    if (tid == 0) {
      s = ls[0] + ls[1] + ls[2] + ls[3];
      stats[0] = 1.f / (s * (1.f / ROWS) + 1e-6f);
    }
    return;
  }
  __shared__ uint16_t As[2][64 * 72];
  __shared__ uint16_t Bs[2][64 * 72];
  int wid = (bid & 7) * 80 + (bid >> 3);             // XCD-contiguous (640 = 8*80)
  int rowg = wid / 5, colg = wid - rowg * 5;
  int wave = tid >> 6, lane = tid & 63;
  int l15 = lane & 15, lg = lane >> 4;
  int wr = wave >> 1, wc = wave & 1;
  int row0 = rowg * 64, n0 = colg * 64;
  int srow = tid >> 3, sseg = tid & 7;
  const uint16_t* agp = xb + (size_t)(row0 + srow) * Hc + sseg * 8;
  const uint16_t* bgp = wcat + (size_t)(n0 + srow) * Hc + sseg * 8;
  int sboff = srow * 72 + sseg * 8;
  int arow = wr * 32 + l15, brow = wc * 32 + l15;

  // stage A = even tiles, stage B = odd tiles (prefetch distance 2)
  bf16x8 a0A = *reinterpret_cast<const bf16x8*>(agp);
  bf16x8 a1A = *reinterpret_cast<const bf16x8*>(agp + (size_t)32 * Hc);
  bf16x8 b0A = *reinterpret_cast<const bf16x8*>(bgp);
  bf16x8 b1A = *reinterpret_cast<const bf16x8*>(bgp + (size_t)32 * Hc);
  bf16x8 a0B = *reinterpret_cast<const bf16x8*>(agp + 64);
  bf16x8 a1B = *reinterpret_cast<const bf16x8*>(agp + (size_t)32 * Hc + 64);
  bf16x8 b0B = *reinterpret_cast<const bf16x8*>(bgp + 64);
  bf16x8 b1B = *reinterpret_cast<const bf16x8*>(bgp + (size_t)32 * Hc + 64);
  f32x4 acc00 = {0.f,0.f,0.f,0.f}, acc01 = {0.f,0.f,0.f,0.f};
  f32x4 acc10 = {0.f,0.f,0.f,0.f}, acc11 = {0.f,0.f,0.f,0.f};

  for (int tt = 0; tt < 16; tt += 2) {
    // even step: buf 0, stage A
    *reinterpret_cast<bf16x8*>(&As[0][sboff]) = a0A;
    *reinterpret_cast<bf16x8*>(&As[0][sboff + 32 * 72]) = a1A;
    *reinterpret_cast<bf16x8*>(&Bs[0][sboff]) = b0A;
    *reinterpret_cast<bf16x8*>(&Bs[0][sboff + 32 * 72]) = b1A;
    if (tt + 2 < 16) {
      int k0 = (tt + 2) * 64;
      a0A = *reinterpret_cast<const bf16x8*>(agp + k0);
      a1A = *reinterpret_cast<const bf16x8*>(agp + (size_t)32 * Hc + k0);
      b0A = *reinterpret_cast<const bf16x8*>(bgp + k0);
      b1A = *reinterpret_cast<const bf16x8*>(bgp + (size_t)32 * Hc + k0);
    }
    __syncthreads();
#pragma unroll
    for (int ks = 0; ks < 2; ++ks) {
      bf16x8 a0 = *reinterpret_cast<const bf16x8*>(&As[0][arow * 72 + ks * 32 + lg * 8]);
      bf16x8 a1 = *reinterpret_cast<const bf16x8*>(&As[0][(arow + 16) * 72 + ks * 32 + lg * 8]);
      bf16x8 b0 = *reinterpret_cast<const bf16x8*>(&Bs[0][brow * 72 + ks * 32 + lg * 8]);
      bf16x8 b1f = *reinterpret_cast<const bf16x8*>(&Bs[0][(brow + 16) * 72 + ks * 32 + lg * 8]);
      acc00 = __builtin_amdgcn_mfma_f32_16x16x32_bf16(a0, b0, acc00, 0, 0, 0);
      acc01 = __builtin_amdgcn_mfma_f32_16x16x32_bf16(a0, b1f, acc01, 0, 0, 0);
      acc10 = __builtin_amdgcn_mfma_f32_16x16x32_bf16(a1, b0, acc10, 0, 0, 0);
      acc11 = __builtin_amdgcn_mfma_f32_16x16x32_bf16(a1, b1f, acc11, 0, 0, 0);
    }
    // odd step: buf 1, stage B (WAR-safe: separated by the barrier above)
    *reinterpret_cast<bf16x8*>(&As[1][sboff]) = a0B;
    *reinterpret_cast<bf16x8*>(&As[1][sboff + 32 * 72]) = a1B;
    *reinterpret_cast<bf16x8*>(&Bs[1][sboff]) = b0B;
    *reinterpret_cast<bf16x8*>(&Bs[1][sboff + 32 * 72]) = b1B;
    if (tt + 3 < 16) {
      int k0 = (tt + 3) * 64;
      a0B = *reinterpret_cast<const bf16x8*>(agp + k0);
      a1B = *reinterpret_cast<const bf16x8*>(agp + (size_t)32 * Hc + k0);
      b0B = *reinterpret_cast<const bf16x8*>(bgp + k0);
      b1B = *reinterpret_cast<const bf16x8*>(bgp + (size_t)32 * Hc + k0);
    }
    __syncthreads();
#pragma unroll
    for (int ks = 0; ks < 2; ++ks) {
      bf16x8 a0 = *reinterpret_cast<const bf16x8*>(&As[1][arow * 72 + ks * 32 + lg * 8]);
      bf16x8 a1 = *reinterpret_cast<const bf16x8*>(&As[1][(arow + 16) * 72 + ks * 32 + lg * 8]);
      bf16x8 b0 = *reinterpret_cast<const bf16x8*>(&Bs[1][brow * 72 + ks * 32 + lg * 8]);
      bf16x8 b1f = *reinterpret_cast<const bf16x8*>(&Bs[1][(brow + 16) * 72 + ks * 32 + lg * 8]);
      acc00 = __builtin_amdgcn_mfma_f32_16x16x32_bf16(a0, b0, acc00, 0, 0, 0);
      acc01 = __builtin_amdgcn_mfma_f32_16x16x32_bf16(a0, b1f, acc01, 0, 0, 0);
      acc10 = __builtin_amdgcn_mfma_f32_16x16x32_bf16(a1, b0, acc10, 0, 0, 0);
      acc11 = __builtin_amdgcn_mfma_f32_16x16x32_bf16(a1, b1f, acc11, 0, 0, 0);
    }
  }
  if (colg < 4) {
    int gc0 = n0 + wc * 32 + l15;
    float b1v0 = b1[gc0],      w2v0 = w2[gc0];
    float b1v1 = b1[gc0 + 16], w2v1 = w2[gc0 + 16];
    int strip = colg * 2 + wc;
    float part0[4], part1[4];
#pragma unroll
    for (int r = 0; r < 4; ++r) {
      float x00 = acc00[r] + b1v0, x01 = acc01[r] + b1v1;
      float x10 = acc10[r] + b1v0, x11 = acc11[r] + b1v1;
      float g00 = 0.5f * x00 * (1.f + erff(x00 * 0.70710678118654752f));
      float g01 = 0.5f * x01 * (1.f + erff(x01 * 0.70710678118654752f));
      float g10 = 0.5f * x10 * (1.f + erff(x10 * 0.70710678118654752f));
      float g11 = 0.5f * x11 * (1.f + erff(x11 * 0.70710678118654752f));
      part0[r] = fmaf(g00, w2v0, g01 * w2v1);
      part1[r] = fmaf(g10, w2v0, g11 * w2v1);
    }
#pragma unroll
    for (int d = 1; d < 16; d <<= 1)
#pragma unroll
      for (int r = 0; r < 4; ++r) {
        part0[r] += __shfl_xor(part0[r], d);
        part1[r] += __shfl_xor(part1[r], d);
      }
    if (l15 == 0) {
#pragma unroll
      for (int r = 0; r < 4; ++r) {
        uncp[(size_t)(row0 + wr * 32 + lg * 4 + r) * 8 + strip] = part0[r];
        uncp[(size_t)(row0 + wr * 32 + 16 + lg * 4 + r) * 8 + strip] = part1[r];
      }
    }
  } else {
    int colA = wc * 32 + l15, colB = colA + 16;
#pragma unroll
    for (int r = 0; r < 4; ++r) {
      int rA = row0 + wr * 32 + lg * 4 + r, rB = rA + 16;
      uint16_t vA = bf16bits(acc00[r]);
      uint16_t vB = (colB == 48) ? (uint16_t)0x3F80u : bf16bits(acc01[r]);
      uint16_t uA = bf16bits(acc10[r]);
      uint16_t uB = (colB == 48) ? (uint16_t)0x3F80u : bf16bits(acc11[r]);
      rq_b[(size_t)rA * 64 + colA] = vA;
      rq_b[(size_t)rA * 64 + colB] = vB;
      rq_b[(size_t)rB * 64 + colA] = uA;
      rq_b[(size_t)rB * 64 + colB] = uB;
    }
  }
}

// ---------- scores via MFMA (swapped operands) + in-register top-8, reg-prefetch ----------
__global__ __launch_bounds__(256) void k_scores_mfma(const uint16_t* __restrict__ rq_b,
                                                     const uint16_t* __restrict__ rk_b,
                                                     uint32_t* __restrict__ cand) {
  int tid = threadIdx.x;
  int wave = tid >> 6, lane = tid & 63;
  int l15 = lane & 15, lg = lane >> 4;
  int rowg = blockIdx.x >> 3, range = blockIdx.x & 7;
  int q0 = rowg * 64 + wave * 16;
  const uint16_t* qp = rq_b + (size_t)(q0 + l15) * 64 + lg * 8;
  bf16x8 qf1 = *reinterpret_cast<const bf16x8*>(qp);
  bf16x8 qf2 = *reinterpret_cast<const bf16x8*>(qp + 32);
  uint32_t top[8];
#pragma unroll
  for (int q = 0; q < 8; ++q) top[q] = 0u;
  int sbase = range * 512;
  const uint16_t* kp = rk_b + (size_t)(sbase + l15) * 64 + lg * 8;
  bf16x8 a1c = *reinterpret_cast<const bf16x8*>(kp);
  bf16x8 a2c = *reinterpret_cast<const bf16x8*>(kp + 32);
  bf16x8 a3c = *reinterpret_cast<const bf16x8*>(kp + 1024);
  bf16x8 a4c = *reinterpret_cast<const bf16x8*>(kp + 1024 + 32);
#pragma unroll
  for (int t = 0; t < 32; t += 2) {
    bf16x8 a1n, a2n, a3n, a4n;
    if (t < 30) {
      const uint16_t* kpn = kp + (size_t)(t + 2) * 1024;
      a1n = *reinterpret_cast<const bf16x8*>(kpn);
      a2n = *reinterpret_cast<const bf16x8*>(kpn + 32);
      a3n = *reinterpret_cast<const bf16x8*>(kpn + 1024);
      a4n = *reinterpret_cast<const bf16x8*>(kpn + 1024 + 32);
    }
    int s0 = sbase + t * 16;
    f32x4 acc0 = {0.f,0.f,0.f,0.f}, acc1 = {0.f,0.f,0.f,0.f};
    acc0 = __builtin_amdgcn_mfma_f32_16x16x32_bf16(a1c, qf1, acc0, 0, 0, 0);
    acc1 = __builtin_amdgcn_mfma_f32_16x16x32_bf16(a3c, qf1, acc1, 0, 0, 0);
    acc0 = __builtin_amdgcn_mfma_f32_16x16x32_bf16(a2c, qf2, acc0, 0, 0, 0);
    acc1 = __builtin_amdgcn_mfma_f32_16x16x32_bf16(a4c, qf2, acc1, 0, 0, 0);
#pragma unroll
    for (int r = 0; r < 4; ++r) top8_insert(top, pack_score(acc0[r], s0 + lg * 4 + r));
#pragma unroll
    for (int r = 0; r < 4; ++r) top8_insert(top, pack_score(acc1[r], s0 + 16 + lg * 4 + r));
    if (t < 30) { a1c = a1n; a2c = a2n; a3c = a3n; a4c = a4n; }
  }
#pragma unroll
  for (int dd = 16; dd <= 32; dd <<= 1) {
    uint32_t o[8];
#pragma unroll
    for (int q = 0; q < 8; ++q) o[q] = __shfl_xor(top[q], dd);
    merge_top8(top, o);
  }
  if (lg == 0) {
    int row = q0 + l15;
#pragma unroll
    for (int q = 0; q < 8; ++q) cand[((size_t)row * 8 + range) * 8 + q] = top[q];
  }
}

// ---------- merge + softmax + gate + gather + output: 4 rows per block ----------
__global__ __launch_bounds__(256) void k_final(const uint16_t* __restrict__ xb,
                                               const uint16_t* __restrict__ avb,
                                               const uint32_t* __restrict__ cand,
                                               const float* __restrict__ log_var,
                                               const float* __restrict__ uncp,
                                               const float* __restrict__ stats,
                                               const float* __restrict__ b2,
                                               const float* __restrict__ gw,
                                               const float* __restrict__ gb,
                                               float* __restrict__ out) {
  int tid = threadIdx.x;
  int wave = tid >> 6, lane = tid & 63;
  int row0 = blockIdx.x * 4;
  __shared__ float ws_[4][8]; __shared__ int wi_[4][8]; __shared__ float sg[4];
  {
    // each wave merges/gates its own row (wave-local, no barrier)
    int row = row0 + wave;
    uint32_t l[8];
    float up = 0.f;
    if (lane < 8) {
      const uint32_t* c = cand + (size_t)row * 64 + lane * 8;
#pragma unroll
      for (int q = 0; q < 8; ++q) l[q] = c[q];
      up = uncp[(size_t)row * 8 + lane];
    } else {
#pragma unroll
      for (int q = 0; q < 8; ++q) l[q] = 0u;
    }
#pragma unroll
    for (int d = 1; d < 8; d <<= 1) {
      uint32_t o[8];
#pragma unroll
      for (int q = 0; q < 8; ++q) o[q] = __shfl_xor(l[q], d);
      merge_top8(l, o);
      up += __shfl_xor(up, d);
    }
    if (lane == 0) {
      float sc[8];
#pragma unroll
      for (int q = 0; q < 8; ++q) sc[q] = unpack_score(l[q]);
      float mx = sc[7];
      float e[8]; float sum = 0.f;
#pragma unroll
      for (int q = 0; q < 8; ++q) { e[q] = expf(sc[q] - mx); sum += e[q]; }
      float inv = 1.f / sum;
#pragma unroll
      for (int q = 0; q < 8; ++q) { ws_[wave][q] = e[q] * inv; wi_[wave][q] = (int)(l[q] & 0xFFFu); }
      float learned = up + b2[0];
      float nv = log_var[row] * stats[0];
      float sig = 1.f / (1.f + expf(-learned));
      float u = nv * 0.5f + sig * 2.5f;
      u = fminf(fmaxf(u, 0.f), 5.f);
      sg[wave] = 1.f / (1.f + expf(-(gw[0] * u + gb[0])));
    }
  }
  __syncthreads();
  int h0 = tid * 4;
#pragma unroll
  for (int rr = 0; rr < 4; ++rr) {
    int row = row0 + rr;
    ushort4 hb = *reinterpret_cast<const ushort4*>(xb + (size_t)row * Hc + h0);
    float ax = 0.f, ay = 0.f, az = 0.f, aw = 0.f;
#pragma unroll
    for (int k = 0; k < 8; ++k) {
      float w = ws_[rr][k];
      ushort4 v = *reinterpret_cast<const ushort4*>(avb + (size_t)wi_[rr][k] * Hc + h0);
      ax = fmaf(w, bf2f(v.x), ax); ay = fmaf(w, bf2f(v.y), ay);
      az = fmaf(w, bf2f(v.z), az); aw = fmaf(w, bf2f(v.w), aw);
    }
    float g = sg[rr];
    float4 o;
    o.x = bf2f(hb.x) + g * ax; o.y = bf2f(hb.y) + g * ay;
    o.z = bf2f(hb.z) + g * az; o.w = bf2f(hb.w) + g * aw;
    *reinterpret_cast<float4*>(out + (size_t)row * Hc + h0) = o;
  }
}

extern "C" void kernel_launch(void* const* d_in, const int* in_sizes, int n_in,
                              void* d_out, int out_size, void* d_ws, size_t ws_size,
                              hipStream_t stream) {
  const float* hidden     = (const float*)d_in[0];
  const float* q_proj_w   = (const float*)d_in[1];
  const float* router_w   = (const float*)d_in[2];
  const float* aux_keys   = (const float*)d_in[3];
  const float* aux_values = (const float*)d_in[4];
  const float* rel        = (const float*)d_in[5];
  const float* unc_w1     = (const float*)d_in[6];
  const float* unc_b1     = (const float*)d_in[7];
  const float* unc_w2     = (const float*)d_in[8];
  const float* unc_b2     = (const float*)d_in[9];
  const float* gate_w1    = (const float*)d_in[10];
  const float* gate_bias  = (const float*)d_in[11];
  float* out = (float*)d_out;

  uint8_t* w = (uint8_t*)d_ws;              // ~28.5 MB used
  uint16_t* xb    = (uint16_t*)w;                 w += (size_t)ROWS * Hc * 2;     // 16 MB
  uint16_t* wcat  = (uint16_t*)w;                 w += (size_t)320 * Hc * 2;      // 640 KB
  uint16_t* avb   = (uint16_t*)w;                 w += (size_t)Nc * Hc * 2;       // 8 MB
  uint16_t* rq_b  = (uint16_t*)w;                 w += (size_t)ROWS * 64 * 2;     // 1 MB
  uint16_t* rk_b  = (uint16_t*)w;                 w += (size_t)Nc * 64 * 2;       // 512 KB
  float* log_var  = (float*)w;                    w += (size_t)ROWS * 4;
  float* uncp     = (float*)w;                    w += (size_t)ROWS * 8 * 4;      // 256 KB
  float* stats    = (float*)w;                    w += 256;
  uint32_t* cand  = (uint32_t*)w;                 w += (size_t)ROWS * 64 * 4;     // 2 MB

  k_prep_all<<<GP_W48 + GP_RK + GP_HB + GP_CVW + GP_CVA, NT, 0, stream>>>(
      hidden, q_proj_w, router_w, aux_keys, aux_values, rel, unc_w1,
      xb, log_var, wcat, avb, rk_b);
  k_xw<<<641, NT, 0, stream>>>(xb, wcat, unc_b1, unc_w2, log_var, stats, uncp, rq_b);
  k_scores_mfma<<<1024, NT, 0, stream>>>(rq_b, rk_b, cand);
  k_final<<<ROWS / 4, NT, 0, stream>>>(xb, avb, cand, log_var, uncp,
                                       stats, unc_b2, gate_w1, gate_bias, out);
}